// Round 6
// baseline (31.838 us; speedup 1.0000x reference)
//
#include <hip/hip_runtime.h>

// Problem constants (B, L, D from reference)
#define BB 64
#define LL 4096
#define DD 256
#define D4 (DD / 4)        // float4 per row = 64
#define PP 128             // chunks per batch
#define RPC (LL / PP)      // rows per chunk = 32
#define CPB 4              // chunks (waves) per block
#define BPB (PP / CPB)     // blocks per batch = 32

// ---------------- Fused: partial sums + block combine + atomic finish ----------------
// 2048 blocks x 256 threads (= 8 blocks/CU, 32 waves/CU = max TLP).
// Block covers 4 adjacent 32-row chunks of ONE batch. Each wave streams its
// chunk (float4/lane, coalesced 1 KiB rows, unroll 8 -> 8 loads in flight),
// LDS-combine across the 4 waves, wave 0 atomically adds the x(1/len)-scaled
// block partial into d_out[b]. atomicAdd is device-scope (cross-XCD safe).
__global__ __launch_bounds__(256) void avg_fused_kernel(
    const float* __restrict__ in,        // [B, L, D]
    const int* __restrict__ len,         // [B] (int32)
    float* __restrict__ out)             // [B, D], pre-zeroed
{
    const int w      = threadIdx.x >> 6;     // wave 0..3
    const int lane   = threadIdx.x & 63;     // 0..63
    const int b      = blockIdx.x / BPB;     // batch (b-major mapping, proven R5)
    const int blockp = blockIdx.x % BPB;

    int lb = len[b];
    if (lb < 1) lb = 1;

    // Whole-block inactive? (uniform across the block -> safe early exit)
    if (blockp * (CPB * RPC) >= lb) return;

    const int p    = blockp * CPB + w;       // this wave's chunk
    const int row0 = p * RPC;

    float4 acc = make_float4(0.f, 0.f, 0.f, 0.f);
    if (row0 < lb) {
        int n = lb - row0;
        if (n > RPC) n = RPC;
        const float4* __restrict__ base =
            (const float4*)(in + (size_t)b * LL * DD) + (size_t)row0 * D4 + lane;
        #pragma unroll 8
        for (int r = 0; r < n; ++r) {
            float4 v = base[(size_t)r * D4];
            acc.x += v.x; acc.y += v.y; acc.z += v.z; acc.w += v.w;
        }
    }

    // Combine 4 waves -> wave 0
    __shared__ float4 sh[CPB - 1][64];
    if (w > 0) sh[w - 1][lane] = acc;
    __syncthreads();

    if (w == 0) {
        #pragma unroll
        for (int i = 0; i < CPB - 1; ++i) {
            float4 v = sh[i][lane];
            acc.x += v.x; acc.y += v.y; acc.z += v.z; acc.w += v.w;
        }
        const float inv = 1.0f / (float)lb;
        float* __restrict__ o = out + (size_t)b * DD + lane * 4;
        atomicAdd(o + 0, acc.x * inv);
        atomicAdd(o + 1, acc.y * inv);
        atomicAdd(o + 2, acc.z * inv);
        atomicAdd(o + 3, acc.w * inv);
    }
}

extern "C" void kernel_launch(void* const* d_in, const int* in_sizes, int n_in,
                              void* d_out, int out_size, void* d_ws, size_t ws_size,
                              hipStream_t stream) {
    const float* in  = (const float*)d_in[0];
    const int*   len = (const int*)d_in[1];
    float*       out = (float*)d_out;

    // d_out is poisoned before timing and not re-zeroed between replays:
    // zero it ourselves every call (graph-capturable async memset node).
    hipMemsetAsync(out, 0, (size_t)out_size * sizeof(float), stream);

    avg_fused_kernel<<<BB * BPB, 256, 0, stream>>>(in, len, out);
}